// Round 8
// baseline (233.834 us; speedup 1.0000x reference)
//
#include <hip/hip_runtime.h>
#include <math.h>

// ---------- types ----------
using f32x4  = __attribute__((ext_vector_type(4))) float;
using bf16x8 = __attribute__((ext_vector_type(8))) short;   // 8 bf16 in 4 VGPRs
using us8    = __attribute__((ext_vector_type(8))) unsigned short;
using us4    = __attribute__((ext_vector_type(4))) unsigned short;

static __device__ __forceinline__ unsigned short f32_bf16(float f) {
    unsigned int u = __float_as_uint(f);
    u += 0x7fffu + ((u >> 16) & 1u);       // round-to-nearest-even
    return (unsigned short)(u >> 16);
}

static __device__ __forceinline__ float fast_exp2(float x) {
    return __builtin_amdgcn_exp2f(x);      // v_exp_f32 (2^x)
}

// pack 2 f32 -> 2 bf16 in one u32 (RNE), single instruction
static __device__ __forceinline__ unsigned int bf16pk(float lo, float hi) {
    unsigned int r;
    asm("v_cvt_pk_bf16_f32 %0, %1, %2" : "=v"(r) : "v"(lo), "v"(hi));
    return r;
}

// global -> LDS direct copy, 16B per lane. LDS dest is wave-uniform base +
// lane*16 (linear); swizzling is done on the per-lane GLOBAL source address.
#define GLOADLDS16(src, dst)                                                          \
    __builtin_amdgcn_global_load_lds(                                                 \
        (const __attribute__((address_space(1))) void*)(src),                         \
        (__attribute__((address_space(3))) void*)(dst), 16, 0, 0)

// ---------- conversion kernels ----------
__global__ __launch_bounds__(256) void conv_x_kernel(const float* __restrict__ x,
                                                     unsigned short* __restrict__ xb) {
    const int i = blockIdx.x * 256 + threadIdx.x;      // over 2M float4s
    const float4 v = ((const float4*)x)[i];
    us4 o;
    o.x = f32_bf16(v.x); o.y = f32_bf16(v.y); o.z = f32_bf16(v.z); o.w = f32_bf16(v.w);
    ((us4*)xb)[i] = o;
}

// transpose + convert the 4 weight matrices: W[k][n] f32 -> WT[n][k] bf16
__global__ __launch_bounds__(256) void conv_wT_kernel(
    const float* __restrict__ Wq, const float* __restrict__ Wk,
    const float* __restrict__ Wv, const float* __restrict__ Wo,
    unsigned short* __restrict__ wqkvT, unsigned short* __restrict__ woT) {
    __shared__ float t[32][33];
    const int z = blockIdx.z;
    const float* W = (z == 0) ? Wq : (z == 1) ? Wk : (z == 2) ? Wv : Wo;
    unsigned short* dst = (z < 3) ? (wqkvT + (size_t)z * 1024 * 1024) : woT;
    const int bx = blockIdx.x * 32, by = blockIdx.y * 32;
    const int tx = threadIdx.x & 31, ty = threadIdx.x >> 5;
#pragma unroll
    for (int i = ty; i < 32; i += 8)
        t[i][tx] = W[(size_t)(by + i) * 1024 + bx + tx];
    __syncthreads();
#pragma unroll
    for (int i = ty; i < 32; i += 8)
        dst[(size_t)(bx + i) * 1024 + by + tx] = f32_bf16(t[tx][i]);
}

// ---------- GEMM (exact round-4 structure, best measured) ----------
// C[M,N] = A[M,K] * Bt[N,K]^T, K=1024. 128x128 tile, 256 thr, single-buffer
// LDS 32 KB (-> 4 blocks/CU co-resident: the implicit cross-block overlap IS
// the pipeline). Operands SWAPPED in mfma (C^T): lane holds 4 consecutive N.
template<int MODE>
__global__ __launch_bounds__(256) void gemm_bt_kernel(
    const unsigned short* __restrict__ A, const unsigned short* __restrict__ Bt,
    const float* __restrict__ bias_q, const float* __restrict__ bias_k,
    const float* __restrict__ bias_v,
    unsigned short* __restrict__ qkv, float* __restrict__ cout) {
    constexpr int K = 1024;
    __shared__ unsigned short As[128 * 64];
    __shared__ unsigned short Bs[128 * 64];
    const int tid = threadIdx.x;
    const int wid = tid >> 6, lane = tid & 63;
    const int bm = blockIdx.x * 128, bn = blockIdx.y * 128;
    const int wr = wid >> 1, wc = wid & 1;       // 2x2 wave grid, 64x64 per wave
    const int l15 = lane & 15, lg = lane >> 4;
    const int srow = lane >> 3;                  // row-within-8 for staging
    const int schunk = (lane & 7) ^ srow;        // pre-swizzled source chunk

    f32x4 acc[4][4] = {};

    for (int kt = 0; kt < K / 64; ++kt) {
#pragma unroll
        for (int i = 0; i < 4; ++i) {
            const int li = wid * 4 + i;          // load instance 0..15, 8 rows each
            const unsigned short* sa =
                A + (size_t)(bm + li * 8 + srow) * K + kt * 64 + schunk * 8;
            GLOADLDS16(sa, &As[li * 512]);
            const unsigned short* sb =
                Bt + (size_t)(bn + li * 8 + srow) * K + kt * 64 + schunk * 8;
            GLOADLDS16(sb, &Bs[li * 512]);
        }
        __syncthreads();
#pragma unroll
        for (int ks = 0; ks < 2; ++ks) {
            bf16x8 af[4], bfr[4];
#pragma unroll
            for (int m = 0; m < 4; ++m) {
                const int row = wr * 64 + m * 16 + l15;
                const int c = (ks * 4 + lg) ^ (row & 7);
                af[m] = *(const bf16x8*)&As[row * 64 + c * 8];
            }
#pragma unroll
            for (int n = 0; n < 4; ++n) {
                const int row = wc * 64 + n * 16 + l15;
                const int c = (ks * 4 + lg) ^ (row & 7);
                bfr[n] = *(const bf16x8*)&Bs[row * 64 + c * 8];
            }
#pragma unroll
            for (int m = 0; m < 4; ++m)
#pragma unroll
                for (int n = 0; n < 4; ++n)
                    acc[m][n] = __builtin_amdgcn_mfma_f32_16x16x32_bf16(
                        bfr[n], af[m], acc[m][n], 0, 0, 0);
        }
        __syncthreads();
    }
    // epilogue (C^T layout): gm = ... + l15 (fixed per lane), gn = ... + lg*4 + r
    if constexpr (MODE == 0) {
        const int which = bn >> 10;               // uniform per block (128 | 1024)
        const int hnb = (bn & 1023) + wc * 64;
        const float* bias = (which == 0) ? bias_q : (which == 1) ? bias_k : bias_v;
        if (which == 2) {
            // V transposed: vT[b][h][d][l]; lane's r-values are consecutive d
#pragma unroll
            for (int m = 0; m < 4; ++m) {
                const int gm = bm + wr * 64 + m * 16 + l15;
                const int b_ = gm >> 10, li2 = gm & 1023;
#pragma unroll
                for (int n = 0; n < 4; ++n) {
                    const int hn0 = hnb + n * 16 + lg * 4;
                    const float4 bb = *(const float4*)&bias[hn0];
                    const float vv[4] = {acc[m][n][0] + bb.x, acc[m][n][1] + bb.y,
                                         acc[m][n][2] + bb.z, acc[m][n][3] + bb.w};
#pragma unroll
                    for (int r = 0; r < 4; ++r) {
                        const int hn = hn0 + r;
                        qkv[16777216 +
                            ((size_t)(b_ * 16 + (hn >> 6)) * 64 + (hn & 63)) * 1024 +
                            li2] = f32_bf16(vv[r]);
                    }
                }
            }
        } else {
            const float qs = (which == 0) ? 0.125f * 1.44269504088896f : 1.0f;
#pragma unroll
            for (int m = 0; m < 4; ++m) {
                const int gm = bm + wr * 64 + m * 16 + l15;
                const size_t rowbase =
                    (((size_t)which * 128 + (gm >> 10) * 16) * 1024 + (gm & 1023)) * 64;
#pragma unroll
                for (int n = 0; n < 4; ++n) {
                    const int hn0 = hnb + n * 16 + lg * 4;   // 4-aligned
                    const float4 bb = *(const float4*)&bias[hn0];
                    const unsigned int w01 = bf16pk((acc[m][n][0] + bb.x) * qs,
                                                    (acc[m][n][1] + bb.y) * qs);
                    const unsigned int w23 = bf16pk((acc[m][n][2] + bb.z) * qs,
                                                    (acc[m][n][3] + bb.w) * qs);
                    uint2 t2; t2.x = w01; t2.y = w23;
                    *(uint2*)&qkv[rowbase + (size_t)(hn0 >> 6) * 65536 + (hn0 & 63)] = t2;
                }
            }
        }
    } else {
#pragma unroll
        for (int m = 0; m < 4; ++m) {
            const int gm = bm + wr * 64 + m * 16 + l15;
#pragma unroll
            for (int n = 0; n < 4; ++n) {
                const int gn0 = bn + wc * 64 + n * 16 + lg * 4;
                const float4 bb = *(const float4*)&bias_q[gn0];
                float4 o;
                o.x = acc[m][n][0] + bb.x; o.y = acc[m][n][1] + bb.y;
                o.z = acc[m][n][2] + bb.z; o.w = acc[m][n][3] + bb.w;
                *(float4*)&cout[(size_t)gm * 1024 + gn0] = o;
            }
        }
    }
}

// ---------- flash attention v3: V direct-from-global (L1/L2 broadcast) ----------
// grid: (B*H, L/128); block 512 = 8 waves, each wave owns 16 q-rows.
// K staged in LDS (all waves share fragments); V fragments load straight from
// global vT[d][l] (L2-resident, identical addresses across waves -> L1 hits).
// One __syncthreads per tile (implicit vmcnt(0) drains the K prefetch, issued
// a full tile of work earlier). P stays in per-wave LDS (no cross-wave deps).
__global__ __launch_bounds__(512, 4) void attn_kernel(
    const unsigned short* __restrict__ qkv, unsigned short* __restrict__ ctx) {
    __shared__ unsigned short Ks[2][4096];    // [key][d] XOR-swizzled, dbuf 16KB
    __shared__ unsigned short Ps[8][1024];    // per-wave P [q][key] swizzled 16KB
    const int bh = blockIdx.x, qt = blockIdx.y;
    const int b = bh >> 4, h = bh & 15;
    const unsigned short* Qp  = qkv + (size_t)bh * 65536;
    const unsigned short* Kp  = qkv + 8388608  + (size_t)bh * 65536;
    const unsigned short* VTp = qkv + 16777216 + (size_t)bh * 65536;  // [64][1024]
    const int tid = threadIdx.x, wid = tid >> 6, lane = tid & 63;
    const int l15 = lane & 15, lg = lane >> 4;
    const int q0 = qt * 128 + wid * 16;
    const int srow = lane >> 3;
    const int schunk = (lane & 7) ^ srow;

    // Q B-fragment: lane holds Q[q=l15][ks*32 + lg*8 ..+8] (pre-scaled log2e/8)
    bf16x8 qf[2];
#pragma unroll
    for (int ks = 0; ks < 2; ++ks)
        qf[ks] = *(const bf16x8*)(Qp + (size_t)(q0 + l15) * 64 + ks * 32 + lg * 8);

    f32x4 oacc[4] = {};
    float lrow = 0.f;     // per-lane PARTIAL sum; cross-lane reduce after loop

    int koff[4][2], poff_r[2], poff_w[4];
#pragma unroll
    for (int nf = 0; nf < 4; ++nf)
#pragma unroll
        for (int ks = 0; ks < 2; ++ks) {
            const int row = nf * 16 + l15;
            koff[nf][ks] = row * 64 + (((ks * 4 + lg) ^ (row & 7)) * 8);
        }
#pragma unroll
    for (int ks = 0; ks < 2; ++ks)
        poff_r[ks] = l15 * 64 + (((ks * 4 + lg) ^ (l15 & 7)) * 8);
#pragma unroll
    for (int nf = 0; nf < 4; ++nf) {
        const int cchunk = nf * 2 + (lg >> 1);
        poff_w[nf] = l15 * 64 + ((cchunk ^ (l15 & 7)) * 8) + (lg & 1) * 4;
    }
    unsigned short* Pw = &Ps[wid][0];
    // V fragment global source: row d = nf*16 + l15, col kt*64 + ks*32 + lg*8
    const unsigned short* vsrc = VTp + (size_t)l15 * 1024 + lg * 8;

#define ATTN_STAGE(KT, BB)                                                            \
    GLOADLDS16(Kp + (size_t)((KT) * 64 + wid * 8 + srow) * 64 + schunk * 8,           \
               &Ks[BB][wid * 512])

    ATTN_STAGE(0, 0);
    __syncthreads();
    for (int kt = 0; kt < 16; ++kt) {
        const int cur = kt & 1;
        if (kt < 15) ATTN_STAGE(kt + 1, cur ^ 1);   // into idle buffer, no hazard

        // V fragments direct from global (overlaps QK^T below; compiler-managed)
        bf16x8 vf[4][2];
#pragma unroll
        for (int nf = 0; nf < 4; ++nf)
#pragma unroll
            for (int ks = 0; ks < 2; ++ks)
                vf[nf][ks] = *(const bf16x8*)(vsrc + (size_t)nf * 16384 + kt * 64 +
                                              ks * 32);

        // S^T = K Q^T : col = q (= l15), row = key-within-16
        const unsigned short* Kb = &Ks[cur][0];
        f32x4 sacc[4] = {};
        __builtin_amdgcn_s_setprio(1);
#pragma unroll
        for (int ks = 0; ks < 2; ++ks)
#pragma unroll
            for (int nf = 0; nf < 4; ++nf) {
                const bf16x8 kf = *(const bf16x8*)&Kb[koff[nf][ks]];
                sacc[nf] = __builtin_amdgcn_mfma_f32_16x16x32_bf16(
                    kf, qf[ks], sacc[nf], 0, 0, 0);
            }
        __builtin_amdgcn_s_setprio(0);

        // no-max softmax: p = 2^s, partial-sum into lrow, pack via cvt_pk
        float rsa = 0.f, rsb = 0.f;
#pragma unroll
        for (int nf = 0; nf < 4; ++nf) {
            const float p0 = fast_exp2(sacc[nf][0]);
            const float p1 = fast_exp2(sacc[nf][1]);
            const float p2 = fast_exp2(sacc[nf][2]);
            const float p3 = fast_exp2(sacc[nf][3]);
            rsa += p0 + p1; rsb += p2 + p3;
            uint2 t; t.x = bf16pk(p0, p1); t.y = bf16pk(p2, p3);
            *(uint2*)&Pw[poff_w[nf]] = t;
        }
        lrow += rsa + rsb;

        // O^T += V^T P : A-frag = vf (registers), B-frag = P rows (q = l15)
        __builtin_amdgcn_s_setprio(1);
#pragma unroll
        for (int ks = 0; ks < 2; ++ks) {
            const bf16x8 pf = *(const bf16x8*)&Pw[poff_r[ks]];
#pragma unroll
            for (int nf = 0; nf < 4; ++nf)
                oacc[nf] = __builtin_amdgcn_mfma_f32_16x16x32_bf16(
                    vf[nf][ks], pf, oacc[nf], 0, 0, 0);
        }
        __builtin_amdgcn_s_setprio(0);

        __syncthreads();   // drains K(kt+1) stage + guards buffer reuse
    }
#undef ATTN_STAGE

    // cross-lane l reduction (4 lanes share q-row: lane bits 4,5)
    lrow += __shfl_xor(lrow, 16);
    lrow += __shfl_xor(lrow, 32);
    const float rl = 1.0f / lrow;

    // normalize (lane-local l) and write ctx bf16 [B][L][D], 8B packed over d
#pragma unroll
    for (int nf = 0; nf < 4; ++nf) {
        uint2 t;
        t.x = bf16pk(oacc[nf][0] * rl, oacc[nf][1] * rl);
        t.y = bf16pk(oacc[nf][2] * rl, oacc[nf][3] * rl);
        *(uint2*)&ctx[((size_t)(b * 1024 + q0 + l15)) * 1024 + h * 64 + nf * 16 +
                      lg * 4] = t;
    }
}

// ---------- relation scores: head_patterns == 1/L exactly ----------
__global__ __launch_bounds__(64) void relation_kernel(
    const float* __restrict__ Wrel, const float* __restrict__ brel,
    float* __restrict__ out) {
    const int t = threadIdx.x;     // 64 = B*R
    const int r = t & 7;
    float s = 0.f;
#pragma unroll
    for (int hh = 0; hh < 16; ++hh) s += Wrel[hh * 8 + r];
    out[8 * 1024 * 1024 + t] = s * (1.0f / 1024.0f) + brel[r];
}

// ---------- launch ----------
extern "C" void kernel_launch(void* const* d_in, const int* in_sizes, int n_in,
                              void* d_out, int out_size, void* d_ws, size_t ws_size,
                              hipStream_t stream) {
    (void)in_sizes; (void)n_in; (void)out_size; (void)ws_size;
    const float* x    = (const float*)d_in[0];
    const float* Wq   = (const float*)d_in[1];
    const float* bq   = (const float*)d_in[2];
    const float* Wk   = (const float*)d_in[3];
    const float* bk   = (const float*)d_in[4];
    const float* Wv   = (const float*)d_in[5];
    const float* bv   = (const float*)d_in[6];
    const float* Wo   = (const float*)d_in[7];
    const float* bo   = (const float*)d_in[8];
    const float* Wrel = (const float*)d_in[9];
    const float* brel = (const float*)d_in[10];
    float* out = (float*)d_out;

    char* ws = (char*)d_ws;
    unsigned short* xb    = (unsigned short*)ws;                           // 16 MB
    unsigned short* wqkvT = (unsigned short*)(ws + 16777216);              // 6 MB
    unsigned short* woT   = (unsigned short*)(ws + 16777216 + 6291456);    // 2 MB
    unsigned short* qkv   = (unsigned short*)(ws + 16777216 + 6291456 + 2097152); // 48 MB
    unsigned short* ctx   = xb;  // xb dead after QKV GEMM -> reuse for ctx

    conv_x_kernel<<<8192, 256, 0, stream>>>(x, xb);
    conv_wT_kernel<<<dim3(32, 32, 4), 256, 0, stream>>>(Wq, Wk, Wv, Wo, wqkvT, woT);
    gemm_bt_kernel<0><<<dim3(64, 24), 256, 0, stream>>>(
        xb, wqkvT, bq, bk, bv, qkv, nullptr);
    attn_kernel<<<dim3(128, 8), 512, 0, stream>>>(qkv, ctx);
    gemm_bt_kernel<1><<<dim3(64, 8), 256, 0, stream>>>(
        ctx, woT, bo, nullptr, nullptr, nullptr, out);
    relation_kernel<<<1, 64, 0, stream>>>(Wrel, brel, out);
}

// Round 9
// 162.769 us; speedup vs baseline: 1.4366x; 1.4366x over previous
//
#include <hip/hip_runtime.h>
#include <math.h>

// ---------- types ----------
using f32x4  = __attribute__((ext_vector_type(4))) float;
using bf16x8 = __attribute__((ext_vector_type(8))) short;   // 8 bf16 in 4 VGPRs
using us8    = __attribute__((ext_vector_type(8))) unsigned short;
using us4    = __attribute__((ext_vector_type(4))) unsigned short;

static __device__ __forceinline__ unsigned short f32_bf16(float f) {
    unsigned int u = __float_as_uint(f);
    u += 0x7fffu + ((u >> 16) & 1u);       // round-to-nearest-even
    return (unsigned short)(u >> 16);
}

static __device__ __forceinline__ float fast_exp2(float x) {
    return __builtin_amdgcn_exp2f(x);      // v_exp_f32 (2^x)
}

// pack 2 f32 -> 2 bf16 in one u32 (RNE), single instruction
static __device__ __forceinline__ unsigned int bf16pk(float lo, float hi) {
    unsigned int r;
    asm("v_cvt_pk_bf16_f32 %0, %1, %2" : "=v"(r) : "v"(lo), "v"(hi));
    return r;
}

// global -> LDS direct copy, 16B per lane. LDS dest is wave-uniform base +
// lane*16 (linear); swizzling is done on the per-lane GLOBAL source address.
#define GLOADLDS16(src, dst)                                                          \
    __builtin_amdgcn_global_load_lds(                                                 \
        (const __attribute__((address_space(1))) void*)(src),                         \
        (__attribute__((address_space(3))) void*)(dst), 16, 0, 0)

// ---------- conversion kernels ----------
__global__ __launch_bounds__(256) void conv_x_kernel(const float* __restrict__ x,
                                                     unsigned short* __restrict__ xb) {
    const int i = blockIdx.x * 256 + threadIdx.x;      // over 2M float4s
    const float4 v = ((const float4*)x)[i];
    us4 o;
    o.x = f32_bf16(v.x); o.y = f32_bf16(v.y); o.z = f32_bf16(v.z); o.w = f32_bf16(v.w);
    ((us4*)xb)[i] = o;
}

// transpose + convert the 4 weight matrices: W[k][n] f32 -> WT[n][k] bf16
__global__ __launch_bounds__(256) void conv_wT_kernel(
    const float* __restrict__ Wq, const float* __restrict__ Wk,
    const float* __restrict__ Wv, const float* __restrict__ Wo,
    unsigned short* __restrict__ wqkvT, unsigned short* __restrict__ woT) {
    __shared__ float t[32][33];
    const int z = blockIdx.z;
    const float* W = (z == 0) ? Wq : (z == 1) ? Wk : (z == 2) ? Wv : Wo;
    unsigned short* dst = (z < 3) ? (wqkvT + (size_t)z * 1024 * 1024) : woT;
    const int bx = blockIdx.x * 32, by = blockIdx.y * 32;
    const int tx = threadIdx.x & 31, ty = threadIdx.x >> 5;
#pragma unroll
    for (int i = ty; i < 32; i += 8)
        t[i][tx] = W[(size_t)(by + i) * 1024 + bx + tx];
    __syncthreads();
#pragma unroll
    for (int i = ty; i < 32; i += 8)
        dst[(size_t)(bx + i) * 1024 + by + tx] = f32_bf16(t[tx][i]);
}

// ---------- GEMM: C[M,N] = A[M,K] * Bt[N,K]^T, K=1024 ----------
// 256x128 tile, 256 thr (4 waves 2x2), per-wave 128x64 (acc[8][4] -> 6 B LDS
// read per MFMA vs 8 at 64x64), BK=64, single-buffer 48 KB LDS -> 2 blocks/CU
// co-resident (R4's proven 2-barrier structure; cross-block overlap is the
// pipeline). Operands SWAPPED in mfma (C^T): lane holds 4 consecutive N.
// MODE 0: QKV epilogue. Q,K -> qkv[which][b][h][l][64] (+bias; Q *= log2e/8),
//         8B packed over d. V -> TRANSPOSED vT[b][h][d][l] (scalar stores).
// MODE 1: out epilogue -> f32 row-major + bias, float4 stores.
template<int MODE>
__global__ __launch_bounds__(256, 2) void gemm_bt_kernel(
    const unsigned short* __restrict__ A, const unsigned short* __restrict__ Bt,
    const float* __restrict__ bias_q, const float* __restrict__ bias_k,
    const float* __restrict__ bias_v,
    unsigned short* __restrict__ qkv, float* __restrict__ cout) {
    constexpr int K = 1024;
    __shared__ unsigned short As[256 * 64];   // 32 KB
    __shared__ unsigned short Bs[128 * 64];   // 16 KB
    const int tid = threadIdx.x;
    const int wid = tid >> 6, lane = tid & 63;
    const int bm = blockIdx.x * 256, bn = blockIdx.y * 128;
    const int wr = wid >> 1, wc = wid & 1;       // 2x2 waves; wave tile 128x64
    const int l15 = lane & 15, lg = lane >> 4;
    const int srow = lane >> 3;                  // row-within-8 for staging
    const int schunk = (lane & 7) ^ srow;        // pre-swizzled source chunk

    f32x4 acc[8][4] = {};

    for (int kt = 0; kt < K / 64; ++kt) {
        // stage A: 32 instances x 8 rows = 256 rows; B: 16 instances = 128 rows
#pragma unroll
        for (int i = 0; i < 8; ++i) {
            const int li = wid * 8 + i;
            GLOADLDS16(A + (size_t)(bm + li * 8 + srow) * K + kt * 64 + schunk * 8,
                       &As[li * 512]);
        }
#pragma unroll
        for (int i = 0; i < 4; ++i) {
            const int li = wid * 4 + i;
            GLOADLDS16(Bt + (size_t)(bn + li * 8 + srow) * K + kt * 64 + schunk * 8,
                       &Bs[li * 512]);
        }
        __syncthreads();
#pragma unroll
        for (int ks = 0; ks < 2; ++ks) {
            bf16x8 bfr[4];
#pragma unroll
            for (int n = 0; n < 4; ++n) {
                const int row = wc * 64 + n * 16 + l15;
                const int c = (ks * 4 + lg) ^ (row & 7);
                bfr[n] = *(const bf16x8*)&Bs[row * 64 + c * 8];
            }
#pragma unroll
            for (int m = 0; m < 8; ++m) {
                const int row = wr * 128 + m * 16 + l15;
                const int c = (ks * 4 + lg) ^ (row & 7);
                const bf16x8 af = *(const bf16x8*)&As[row * 64 + c * 8];
#pragma unroll
                for (int n = 0; n < 4; ++n)
                    acc[m][n] = __builtin_amdgcn_mfma_f32_16x16x32_bf16(
                        bfr[n], af, acc[m][n], 0, 0, 0);
            }
        }
        __syncthreads();
    }
    // epilogue (C^T layout): gm = ... + l15 (fixed per lane), gn = ... + lg*4 + r
    if constexpr (MODE == 0) {
        const int which = bn >> 10;               // uniform per block (128 | 1024)
        const int hnb = (bn & 1023) + wc * 64;
        const float* bias = (which == 0) ? bias_q : (which == 1) ? bias_k : bias_v;
        if (which == 2) {
            // V transposed: vT[b][h][d][l]; lane's r-values are consecutive d
#pragma unroll
            for (int m = 0; m < 8; ++m) {
                const int gm = bm + wr * 128 + m * 16 + l15;
                const int b_ = gm >> 10, li2 = gm & 1023;
#pragma unroll
                for (int n = 0; n < 4; ++n) {
                    const int hn0 = hnb + n * 16 + lg * 4;
                    const float4 bb = *(const float4*)&bias[hn0];
                    const float vv[4] = {acc[m][n][0] + bb.x, acc[m][n][1] + bb.y,
                                         acc[m][n][2] + bb.z, acc[m][n][3] + bb.w};
#pragma unroll
                    for (int r = 0; r < 4; ++r) {
                        const int hn = hn0 + r;
                        qkv[16777216 +
                            ((size_t)(b_ * 16 + (hn >> 6)) * 64 + (hn & 63)) * 1024 +
                            li2] = f32_bf16(vv[r]);
                    }
                }
            }
        } else {
            const float qs = (which == 0) ? 0.125f * 1.44269504088896f : 1.0f;
#pragma unroll
            for (int m = 0; m < 8; ++m) {
                const int gm = bm + wr * 128 + m * 16 + l15;
                const size_t rowbase =
                    (((size_t)which * 128 + (gm >> 10) * 16) * 1024 + (gm & 1023)) * 64;
#pragma unroll
                for (int n = 0; n < 4; ++n) {
                    const int hn0 = hnb + n * 16 + lg * 4;   // 4-aligned
                    const float4 bb = *(const float4*)&bias[hn0];
                    const unsigned int w01 = bf16pk((acc[m][n][0] + bb.x) * qs,
                                                    (acc[m][n][1] + bb.y) * qs);
                    const unsigned int w23 = bf16pk((acc[m][n][2] + bb.z) * qs,
                                                    (acc[m][n][3] + bb.w) * qs);
                    uint2 t2; t2.x = w01; t2.y = w23;
                    *(uint2*)&qkv[rowbase + (size_t)(hn0 >> 6) * 65536 + (hn0 & 63)] = t2;
                }
            }
        }
    } else {
#pragma unroll
        for (int m = 0; m < 8; ++m) {
            const int gm = bm + wr * 128 + m * 16 + l15;
#pragma unroll
            for (int n = 0; n < 4; ++n) {
                const int gn0 = bn + wc * 64 + n * 16 + lg * 4;
                const float4 bb = *(const float4*)&bias_q[gn0];
                float4 o;
                o.x = acc[m][n][0] + bb.x; o.y = acc[m][n][1] + bb.y;
                o.z = acc[m][n][2] + bb.z; o.w = acc[m][n][3] + bb.w;
                *(float4*)&cout[(size_t)gm * 1024 + gn0] = o;
            }
        }
    }
}

// ---------- flash attention (round-4 version: swapped-operand, O^T, no-max) ----------
// grid: (B*H, L/128); block 512 = 8 waves, each wave owns 16 q-rows.
__global__ __launch_bounds__(512) void attn_kernel(
    const unsigned short* __restrict__ qkv, unsigned short* __restrict__ ctx) {
    __shared__ unsigned short Ks[2][4096];    // [key][d] XOR-swizzled, dbuf 16KB
    __shared__ unsigned short VTs[2][4096];   // [d][key] XOR-swizzled, dbuf 16KB
    __shared__ unsigned short Ps[8][1024];    // per-wave P [q][key] swizzled 16KB
    const int bh = blockIdx.x, qt = blockIdx.y;
    const int b = bh >> 4, h = bh & 15;
    const unsigned short* Qp  = qkv + (size_t)bh * 65536;
    const unsigned short* Kp  = qkv + 8388608  + (size_t)bh * 65536;
    const unsigned short* VTp = qkv + 16777216 + (size_t)bh * 65536;  // [64][1024]
    const int tid = threadIdx.x, wid = tid >> 6, lane = tid & 63;
    const int l15 = lane & 15, lg = lane >> 4;
    const int q0 = qt * 128 + wid * 16;
    const int srow = lane >> 3;
    const int schunk = (lane & 7) ^ srow;

    bf16x8 qf[2];
#pragma unroll
    for (int ks = 0; ks < 2; ++ks)
        qf[ks] = *(const bf16x8*)(Qp + (size_t)(q0 + l15) * 64 + ks * 32 + lg * 8);

    f32x4 oacc[4] = {};
    float lrow = 0.f;

    int koff[4][2], poff_r[2], poff_w[4];
#pragma unroll
    for (int nf = 0; nf < 4; ++nf)
#pragma unroll
        for (int ks = 0; ks < 2; ++ks) {
            const int row = nf * 16 + l15;
            koff[nf][ks] = row * 64 + (((ks * 4 + lg) ^ (row & 7)) * 8);
        }
#pragma unroll
    for (int ks = 0; ks < 2; ++ks)
        poff_r[ks] = l15 * 64 + (((ks * 4 + lg) ^ (l15 & 7)) * 8);
#pragma unroll
    for (int nf = 0; nf < 4; ++nf) {
        const int cchunk = nf * 2 + (lg >> 1);
        poff_w[nf] = l15 * 64 + ((cchunk ^ (l15 & 7)) * 8) + (lg & 1) * 4;
    }
    unsigned short* Pw = &Ps[wid][0];

#define ATTN_STAGE(KT, BB)                                                            \
    do {                                                                              \
        GLOADLDS16(Kp + (size_t)((KT) * 64 + wid * 8 + srow) * 64 + schunk * 8,       \
                   &Ks[BB][wid * 512]);                                               \
        GLOADLDS16(VTp + (size_t)(wid * 8 + srow) * 1024 + (KT) * 64 + schunk * 8,    \
                   &VTs[BB][wid * 512]);                                              \
    } while (0)

    ATTN_STAGE(0, 0);
    for (int kt = 0; kt < 16; ++kt) {
        const int cur = kt & 1;
        if (kt < 15) {
            ATTN_STAGE(kt + 1, cur ^ 1);
            asm volatile("s_waitcnt vmcnt(2)" ::: "memory");
        } else {
            asm volatile("s_waitcnt vmcnt(0)" ::: "memory");
        }
        __builtin_amdgcn_s_barrier();

        const unsigned short* Kb = &Ks[cur][0];
        const unsigned short* Vb = &VTs[cur][0];

        f32x4 sacc[4] = {};
        __builtin_amdgcn_s_setprio(1);
#pragma unroll
        for (int ks = 0; ks < 2; ++ks)
#pragma unroll
            for (int nf = 0; nf < 4; ++nf) {
                const bf16x8 kf = *(const bf16x8*)&Kb[koff[nf][ks]];
                sacc[nf] = __builtin_amdgcn_mfma_f32_16x16x32_bf16(
                    kf, qf[ks], sacc[nf], 0, 0, 0);
            }
        __builtin_amdgcn_s_setprio(0);

        float rsa = 0.f, rsb = 0.f;
#pragma unroll
        for (int nf = 0; nf < 4; ++nf) {
            const float p0 = fast_exp2(sacc[nf][0]);
            const float p1 = fast_exp2(sacc[nf][1]);
            const float p2 = fast_exp2(sacc[nf][2]);
            const float p3 = fast_exp2(sacc[nf][3]);
            rsa += p0 + p1; rsb += p2 + p3;
            uint2 t; t.x = bf16pk(p0, p1); t.y = bf16pk(p2, p3);
            *(uint2*)&Pw[poff_w[nf]] = t;
        }
        lrow += rsa + rsb;

        __builtin_amdgcn_s_setprio(1);
#pragma unroll
        for (int ks = 0; ks < 2; ++ks) {
            const bf16x8 pf = *(const bf16x8*)&Pw[poff_r[ks]];
#pragma unroll
            for (int nf = 0; nf < 4; ++nf) {
                const bf16x8 vf = *(const bf16x8*)&Vb[koff[nf][ks]];
                oacc[nf] = __builtin_amdgcn_mfma_f32_16x16x32_bf16(
                    vf, pf, oacc[nf], 0, 0, 0);
            }
        }
        __builtin_amdgcn_s_setprio(0);

        __builtin_amdgcn_s_barrier();
    }
#undef ATTN_STAGE

    lrow += __shfl_xor(lrow, 16);
    lrow += __shfl_xor(lrow, 32);
    const float rl = 1.0f / lrow;

#pragma unroll
    for (int nf = 0; nf < 4; ++nf) {
        uint2 t;
        t.x = bf16pk(oacc[nf][0] * rl, oacc[nf][1] * rl);
        t.y = bf16pk(oacc[nf][2] * rl, oacc[nf][3] * rl);
        *(uint2*)&ctx[((size_t)(b * 1024 + q0 + l15)) * 1024 + h * 64 + nf * 16 +
                      lg * 4] = t;
    }
}

// ---------- relation scores: head_patterns == 1/L exactly ----------
__global__ __launch_bounds__(64) void relation_kernel(
    const float* __restrict__ Wrel, const float* __restrict__ brel,
    float* __restrict__ out) {
    const int t = threadIdx.x;     // 64 = B*R
    const int r = t & 7;
    float s = 0.f;
#pragma unroll
    for (int hh = 0; hh < 16; ++hh) s += Wrel[hh * 8 + r];
    out[8 * 1024 * 1024 + t] = s * (1.0f / 1024.0f) + brel[r];
}

// ---------- launch ----------
extern "C" void kernel_launch(void* const* d_in, const int* in_sizes, int n_in,
                              void* d_out, int out_size, void* d_ws, size_t ws_size,
                              hipStream_t stream) {
    (void)in_sizes; (void)n_in; (void)out_size; (void)ws_size;
    const float* x    = (const float*)d_in[0];
    const float* Wq   = (const float*)d_in[1];
    const float* bq   = (const float*)d_in[2];
    const float* Wk   = (const float*)d_in[3];
    const float* bk   = (const float*)d_in[4];
    const float* Wv   = (const float*)d_in[5];
    const float* bv   = (const float*)d_in[6];
    const float* Wo   = (const float*)d_in[7];
    const float* bo   = (const float*)d_in[8];
    const float* Wrel = (const float*)d_in[9];
    const float* brel = (const float*)d_in[10];
    float* out = (float*)d_out;

    char* ws = (char*)d_ws;
    unsigned short* xb    = (unsigned short*)ws;                           // 16 MB
    unsigned short* wqkvT = (unsigned short*)(ws + 16777216);              // 6 MB
    unsigned short* woT   = (unsigned short*)(ws + 16777216 + 6291456);    // 2 MB
    unsigned short* qkv   = (unsigned short*)(ws + 16777216 + 6291456 + 2097152); // 48 MB
    unsigned short* ctx   = xb;  // xb dead after QKV GEMM -> reuse for ctx

    conv_x_kernel<<<8192, 256, 0, stream>>>(x, xb);
    conv_wT_kernel<<<dim3(32, 32, 4), 256, 0, stream>>>(Wq, Wk, Wv, Wo, wqkvT, woT);
    gemm_bt_kernel<0><<<dim3(32, 24), 256, 0, stream>>>(
        xb, wqkvT, bq, bk, bv, qkv, nullptr);
    attn_kernel<<<dim3(128, 8), 512, 0, stream>>>(qkv, ctx);
    gemm_bt_kernel<1><<<dim3(32, 8), 256, 0, stream>>>(
        ctx, woT, bo, nullptr, nullptr, nullptr, out);
    relation_kernel<<<1, 64, 0, stream>>>(Wrel, brel, out);
}